// Round 4
// baseline (78.615 us; speedup 1.0000x reference)
//
#include <hip/hip_runtime.h>
#include <math.h>

#define BATCH 65536
#define XPER  576      // 24*24 floats per element
#define NBLK  1024
#define EPB   64       // elements per block
#define GPI   16       // elements per staging tile
#define ITERS (EPB / GPI)
#define IMGS  146      // LDS image stride in float4 (584 floats, pad 8)

// ws float layout: [0..3] sum_z, [4..7] sum_z2   (zeroed by memset node)

// ---------------------------------------------------------------- K1
__global__ __launch_bounds__(256, 4) void circuit_kernel(
        const float* __restrict__ x, const float* __restrict__ params,
        float* __restrict__ out, float* __restrict__ accums) {
    __shared__ float sx[GPI * IMGS * 4];   // 37376 B, padded image stride
    __shared__ float smisc[512];           // U (init phase), then vbuf[16][16]
    __shared__ float sg[48];               // 8 gates x {c,s,epr,epi,emr,emi}
    __shared__ float spart[8];

    const int t = threadIdx.x;
    const int e = t >> 4;      // image within tile of 16
    const int p = t & 15;      // pool index == state row owned by this lane

    if (t < 8) {
        spart[t] = 0.0f;
        float phi   = params[t * 3 + 0];
        float theta = params[t * 3 + 1];
        float omega = params[t * 3 + 2];
        float apo = 0.5f * (phi + omega), amo = 0.5f * (phi - omega);
        sg[t * 6 + 0] = cosf(0.5f * theta);
        sg[t * 6 + 1] = sinf(0.5f * theta);
        sg[t * 6 + 2] = cosf(apo);           // epr (ep = e^{-i(phi+omega)/2})
        sg[t * 6 + 3] = -sinf(apo);          // epi
        sg[t * 6 + 4] = cosf(amo);           // emr (em = e^{+i(phi-omega)/2})
        sg[t * 6 + 5] = sinf(amo);           // emi
    }

    // ---- prologue: prefetch tile 0 into registers (coalesced float4)
    const int base = blockIdx.x * EPB;
    float4 r[9];
    {
        const float4* src = (const float4*)(x + (size_t)base * XPER);
#pragma unroll
        for (int k = 0; k < 9; ++k) r[k] = src[k * 256 + t];
    }
    __syncthreads();

    // ---- fold circuit into U (lane j owns column j), write to smisc
    if (t < 16) {
        const int j = t;
        float Mr[16], Mi[16];
#pragma unroll
        for (int i = 0; i < 16; ++i) { Mr[i] = (i == j) ? 1.0f : 0.0f; Mi[i] = 0.0f; }
#pragma unroll
        for (int l = 0; l < 2; ++l) {
#pragma unroll
            for (int w = 0; w < 4; ++w) {
                const int g = l * 4 + w;
                float c   = sg[g * 6 + 0], s   = sg[g * 6 + 1];
                float epr = sg[g * 6 + 2], epi = sg[g * 6 + 3];
                float emr = sg[g * 6 + 4], emi = sg[g * 6 + 5];
                float m00r =  epr * c, m00i =  epi * c;
                float m01r = -emr * s, m01i = -emi * s;
                float m10r =  emr * s, m10i = -emi * s;
                float m11r =  epr * c, m11i = -epi * c;
                const int mask = 1 << (3 - w);
#pragma unroll
                for (int i = 0; i < 16; ++i) {
                    if (i & mask) continue;
                    int i1 = i | mask;
                    float r0 = Mr[i],  q0 = Mi[i];
                    float r1 = Mr[i1], q1 = Mi[i1];
                    Mr[i]  = m00r * r0 - m00i * q0 + m01r * r1 - m01i * q1;
                    Mi[i]  = m00r * q0 + m00i * r0 + m01r * q1 + m01i * r1;
                    Mr[i1] = m10r * r0 - m10i * q0 + m11r * r1 - m11i * q1;
                    Mi[i1] = m10r * q0 + m10i * r0 + m11r * q1 + m11i * r1;
                }
            }
            const int rr = (l % 3) + 1;
#pragma unroll
            for (int w = 0; w < 4; ++w) {
                int tq = (w + rr) & 3;
                int cb = 3 - w, tb = 3 - tq;
#pragma unroll
                for (int i = 0; i < 16; ++i) {
                    int pi = i ^ (((i >> cb) & 1) << tb);
                    if (pi > i) {
                        float tr = Mr[i]; Mr[i] = Mr[pi]; Mr[pi] = tr;
                        float ti = Mi[i]; Mi[i] = Mi[pi]; Mi[pi] = ti;
                    }
                }
            }
        }
#pragma unroll
        for (int i = 0; i < 16; ++i) {
            smisc[i * 16 + j]       = Mr[i];
            smisc[256 + i * 16 + j] = Mi[i];
        }
    }
    __syncthreads();

    // U row p -> registers (float4 LDS reads, once)
    float ur[16], ui[16];
    {
        const float4* u4 = (const float4*)(smisc + p * 16);
        const float4* v4 = (const float4*)(smisc + 256 + p * 16);
#pragma unroll
        for (int q = 0; q < 4; ++q) {
            float4 a = u4[q], b = v4[q];
            ur[4 * q + 0] = a.x; ur[4 * q + 1] = a.y; ur[4 * q + 2] = a.z; ur[4 * q + 3] = a.w;
            ui[4 * q + 0] = b.x; ui[4 * q + 1] = b.y; ui[4 * q + 2] = b.z; ui[4 * q + 3] = b.w;
        }
    }
    __syncthreads();   // smisc now free to reuse as vbuf

    // writer lane -> output channel (z_w lives at group-lane 1<<(3-w))
    int c = -1;
    if      (p == 8) c = 0;
    else if (p == 4) c = 1;
    else if (p == 2) c = 2;
    else if (p == 1) c = 3;

    float accz = 0.0f, accz2 = 0.0f;

    for (int it = 0; it < ITERS; ++it) {
        // ---- write current tile regs -> LDS (padded image stride)
#pragma unroll
        for (int k = 0; k < 9; ++k) {
            int idx = k * 256 + t;           // 0..2303 (16 img x 144 f4)
            int img = idx / 144;             // magic-mul
            int rem = idx - img * 144;
            ((float4*)sx)[img * IMGS + rem] = r[k];
        }
        // ---- T14: issue next tile's loads immediately (hide under compute)
        if (it + 1 < ITERS) {
            const float4* src = (const float4*)(x + (size_t)(base + (it + 1) * GPI) * XPER);
#pragma unroll
            for (int k = 0; k < 9; ++k) r[k] = src[k * 256 + t];
        }
        __syncthreads();

        // ---- 6x6 average pool (float2 reads, 4-way max bank conflict)
        const float* bs = sx + e * (IMGS * 4) + (p >> 2) * 144 + (p & 3) * 6;
        float sum = 0.0f;
#pragma unroll
        for (int i = 0; i < 6; ++i) {
            const float2* rp = (const float2*)(bs + i * 24);
            float2 a2 = rp[0], b2 = rp[1], d2 = rp[2];
            sum += a2.x + a2.y + b2.x + b2.y + d2.x + d2.y;
        }
        float v = sum * (1.0f / 36.0f);
        smisc[e * 16 + p] = v;               // vbuf (2-way, free)
        __syncthreads();

        // ---- read full pooled vector (broadcast b128), n2 + matvec local
        float vv[16];
        {
            const float4* vb = (const float4*)(smisc + e * 16);
#pragma unroll
            for (int q = 0; q < 4; ++q) {
                float4 a = vb[q];
                vv[4 * q + 0] = a.x; vv[4 * q + 1] = a.y;
                vv[4 * q + 2] = a.z; vv[4 * q + 3] = a.w;
            }
        }
        float n2 = 0.0f, sr = 0.0f, si = 0.0f;
#pragma unroll
        for (int j = 0; j < 16; ++j) {
            n2 = fmaf(vv[j], vv[j], n2);
            sr = fmaf(ur[j], vv[j], sr);
            si = fmaf(ui[j], vv[j], si);
        }
        float prob = (sr * sr + si * si) / n2;

        // ---- 16-pt Walsh-Hadamard across the 16-lane group
        float a = prob, o;
        o = __shfl_xor(a, 1); a = (t & 1) ? (o - a) : (a + o);
        o = __shfl_xor(a, 2); a = (t & 2) ? (o - a) : (a + o);
        o = __shfl_xor(a, 4); a = (t & 4) ? (o - a) : (a + o);
        o = __shfl_xor(a, 8); a = (t & 8) ? (o - a) : (a + o);

        if (c >= 0) {
            const int img = base + it * GPI + e;
            out[(size_t)img * 4 + c] = a;    // raw z, normalized by K2
            accz  += a;
            accz2 += a * a;
        }
        __syncthreads();   // vbuf + sx reads done before next tile's writes
    }

    if (c >= 0) {
        atomicAdd(&spart[c], accz);
        atomicAdd(&spart[4 + c], accz2);
    }
    __syncthreads();
    if (t < 8) atomicAdd(&accums[t], spart[t]);
}

// ---------------------------------------------------------------- K2
__global__ __launch_bounds__(256) void bn_apply(float* __restrict__ out,
                                                const float* __restrict__ accums,
                                                const float* __restrict__ gamma,
                                                const float* __restrict__ beta) {
    __shared__ float sc[8];
    const int t = threadIdx.x;
    if (t < 4) {
        float mu  = accums[t] * (1.0f / BATCH);
        float var = accums[4 + t] * (1.0f / BATCH) - mu * mu;
        float a = gamma[t] * rsqrtf(var + 1e-5f);
        sc[t]     = a;
        sc[4 + t] = beta[t] - mu * a;
    }
    __syncthreads();
    int i = blockIdx.x * 256 + t;   // one float4 (one element) each
    float4 z = ((float4*)out)[i];
    z.x = fmaf(z.x, sc[0], sc[4]);
    z.y = fmaf(z.y, sc[1], sc[5]);
    z.z = fmaf(z.z, sc[2], sc[6]);
    z.w = fmaf(z.w, sc[3], sc[7]);
    ((float4*)out)[i] = z;
}

extern "C" void kernel_launch(void* const* d_in, const int* in_sizes, int n_in,
                              void* d_out, int out_size, void* d_ws, size_t ws_size,
                              hipStream_t stream) {
    const float* x      = (const float*)d_in[0];
    const float* params = (const float*)d_in[1];
    const float* gamma  = (const float*)d_in[2];
    const float* beta   = (const float*)d_in[3];
    float* out = (float*)d_out;
    float* ws  = (float*)d_ws;

    hipMemsetAsync(ws, 0, 8 * sizeof(float), stream);   // zero BN accumulators
    hipLaunchKernelGGL(circuit_kernel, dim3(NBLK), dim3(256), 0, stream,
                       x, params, out, ws);
    hipLaunchKernelGGL(bn_apply, dim3(BATCH / 256), dim3(256), 0, stream,
                       out, ws, gamma, beta);
}

// Round 5
// 41.987 us; speedup vs baseline: 1.8724x; 1.8724x over previous
//
#include <hip/hip_runtime.h>
#include <math.h>

#define BATCH 65536
#define XPER  576              // 24*24 floats per image
#define NBLK  512
#define EPB   128              // images per block
#define GPI   16               // images per tile
#define ITERS (EPB / GPI)      // 8
#define TILEF (GPI * XPER)     // 9216 floats per tile

// ws float layout: [0..3] sum_z, [4..7] sum_z2   (zeroed by memset node)

__device__ __forceinline__ void gload16(const float* g, float* l) {
    __builtin_amdgcn_global_load_lds(
        (__attribute__((address_space(1))) void*)(g),
        (__attribute__((address_space(3))) void*)(l),
        16, 0, 0);
}

// ---------------------------------------------------------------- K1
__global__ __launch_bounds__(256) void circuit_kernel(
        const float* __restrict__ x, const float* __restrict__ params,
        float* __restrict__ out, float* __restrict__ accums) {
    __shared__ float sx[2][TILEF];     // 73728 B double-buffered tile
    __shared__ float sU[512];          // Ur row-major, then Ui
    __shared__ float sg[48];           // 8 gates x {c,s,epr,epi,emr,emi}
    __shared__ float spart[8];

    const int t    = threadIdx.x;
    const int wid  = t >> 6;           // wave id (0..3)
    const int lane = t & 63;
    const int e    = t >> 4;           // image within tile (0..15)
    const int p    = t & 15;           // pool index == state row

    const size_t base = (size_t)blockIdx.x * EPB;

    // ---- stage tile 0 (async, fires before the trig/fold work)
    {
        const float* src = x + base * XPER + wid * 2304 + lane * 4;
        float* dst = &sx[0][wid * 2304];
#pragma unroll
        for (int j = 0; j < 9; ++j) gload16(src + j * 256, dst + j * 256);
    }

    if (t < 8) {
        spart[t] = 0.0f;
        float phi   = params[t * 3 + 0];
        float theta = params[t * 3 + 1];
        float omega = params[t * 3 + 2];
        float apo = 0.5f * (phi + omega), amo = 0.5f * (phi - omega);
        sg[t * 6 + 0] = cosf(0.5f * theta);
        sg[t * 6 + 1] = sinf(0.5f * theta);
        sg[t * 6 + 2] = cosf(apo);           // epr (ep = e^{-i(phi+omega)/2})
        sg[t * 6 + 3] = -sinf(apo);          // epi
        sg[t * 6 + 4] = cosf(amo);           // emr (em = e^{+i(phi-omega)/2})
        sg[t * 6 + 5] = sinf(amo);           // emi
    }
    __syncthreads();

    // ---- fold circuit into U (lane j owns column j of M; state' = M state)
    if (t < 16) {
        const int j = t;
        float Mr[16], Mi[16];
#pragma unroll
        for (int i = 0; i < 16; ++i) { Mr[i] = (i == j) ? 1.0f : 0.0f; Mi[i] = 0.0f; }
#pragma unroll
        for (int l = 0; l < 2; ++l) {
#pragma unroll
            for (int w = 0; w < 4; ++w) {
                const int g = l * 4 + w;
                float c   = sg[g * 6 + 0], s   = sg[g * 6 + 1];
                float epr = sg[g * 6 + 2], epi = sg[g * 6 + 3];
                float emr = sg[g * 6 + 4], emi = sg[g * 6 + 5];
                float m00r =  epr * c, m00i =  epi * c;
                float m01r = -emr * s, m01i = -emi * s;
                float m10r =  emr * s, m10i = -emi * s;
                float m11r =  epr * c, m11i = -epi * c;
                const int mask = 1 << (3 - w);
#pragma unroll
                for (int i = 0; i < 16; ++i) {
                    if (i & mask) continue;
                    int i1 = i | mask;
                    float r0 = Mr[i],  q0 = Mi[i];
                    float r1 = Mr[i1], q1 = Mi[i1];
                    Mr[i]  = m00r * r0 - m00i * q0 + m01r * r1 - m01i * q1;
                    Mi[i]  = m00r * q0 + m00i * r0 + m01r * q1 + m01i * r1;
                    Mr[i1] = m10r * r0 - m10i * q0 + m11r * r1 - m11i * q1;
                    Mi[i1] = m10r * q0 + m10i * r0 + m11r * q1 + m11i * r1;
                }
            }
            const int rr = (l % 3) + 1;
#pragma unroll
            for (int w = 0; w < 4; ++w) {
                int tq = (w + rr) & 3;
                int cb = 3 - w, tb = 3 - tq;
#pragma unroll
                for (int i = 0; i < 16; ++i) {
                    int pi = i ^ (((i >> cb) & 1) << tb);
                    if (pi > i) {
                        float tr = Mr[i]; Mr[i] = Mr[pi]; Mr[pi] = tr;
                        float ti = Mi[i]; Mi[i] = Mi[pi]; Mi[pi] = ti;
                    }
                }
            }
        }
#pragma unroll
        for (int i = 0; i < 16; ++i) {
            sU[i * 16 + j]       = Mr[i];
            sU[256 + i * 16 + j] = Mi[i];
        }
    }
    __syncthreads();

    // ---- U row p -> registers (float4 LDS reads, once)
    float ur[16], ui[16];
    {
        const float4* u4 = (const float4*)(sU + p * 16);
        const float4* v4 = (const float4*)(sU + 256 + p * 16);
#pragma unroll
        for (int q = 0; q < 4; ++q) {
            float4 a = u4[q], b = v4[q];
            ur[4 * q + 0] = a.x; ur[4 * q + 1] = a.y; ur[4 * q + 2] = a.z; ur[4 * q + 3] = a.w;
            ui[4 * q + 0] = b.x; ui[4 * q + 1] = b.y; ui[4 * q + 2] = b.z; ui[4 * q + 3] = b.w;
        }
    }

    // writer lane -> output channel (z_w lives at group-lane 1<<(3-w))
    int c = -1;
    if      (p == 8) c = 0;
    else if (p == 4) c = 1;
    else if (p == 2) c = 2;
    else if (p == 1) c = 3;

    float zbuf[ITERS];
    float accz = 0.0f, accz2 = 0.0f;

    // ---- main pipeline: counted vmcnt, raw barriers, loads span barriers
#pragma unroll
    for (int it = 0; it < ITERS; ++it) {
        if (it + 1 < ITERS) {
            const float* src = x + (base + (size_t)(it + 1) * GPI) * XPER
                                 + wid * 2304 + lane * 4;
            float* dst = &sx[(it + 1) & 1][wid * 2304];
#pragma unroll
            for (int j = 0; j < 9; ++j) gload16(src + j * 256, dst + j * 256);
            asm volatile("s_waitcnt vmcnt(9)" ::: "memory");  // tile it done
        } else {
            asm volatile("s_waitcnt vmcnt(0)" ::: "memory");
        }
        __builtin_amdgcn_s_barrier();

        // ---- 6x6 average pool (float2 reads from current buffer)
        const float* bs = sx[it & 1] + e * XPER + (p >> 2) * 144 + (p & 3) * 6;
        float sum = 0.0f;
#pragma unroll
        for (int i = 0; i < 6; ++i) {
            const float2* rp = (const float2*)(bs + i * 24);
            float2 a2 = rp[0], b2 = rp[1], d2 = rp[2];
            sum += a2.x + a2.y + b2.x + b2.y + d2.x + d2.y;
        }
        float v = sum * (1.0f / 36.0f);

        // norm^2 over the 16-lane group
        float n2 = v * v;
        n2 += __shfl_xor(n2, 1);
        n2 += __shfl_xor(n2, 2);
        n2 += __shfl_xor(n2, 4);
        n2 += __shfl_xor(n2, 8);

        // state_p = sum_j U[p][j] * v_j   (input state is real)
        float sr = 0.0f, si = 0.0f;
#pragma unroll
        for (int j = 0; j < 16; ++j) {
            float vj = __shfl(v, j, 16);
            sr = fmaf(ur[j], vj, sr);
            si = fmaf(ui[j], vj, si);
        }
        float prob = (sr * sr + si * si) / n2;

        // 16-pt Walsh-Hadamard across the 16-lane group
        float a = prob, o;
        o = __shfl_xor(a, 1); a = (t & 1) ? (o - a) : (a + o);
        o = __shfl_xor(a, 2); a = (t & 2) ? (o - a) : (a + o);
        o = __shfl_xor(a, 4); a = (t & 4) ? (o - a) : (a + o);
        o = __shfl_xor(a, 8); a = (t & 8) ? (o - a) : (a + o);

        zbuf[it] = a;
        if (c >= 0) { accz += a; accz2 += a * a; }

        __builtin_amdgcn_s_barrier();   // all reads of buf[it&1] done
    }

    // ---- epilogue: stores out of the loop (keeps vmcnt counts exact)
    if (c >= 0) {
#pragma unroll
        for (int it = 0; it < ITERS; ++it)
            out[(base + (size_t)it * GPI + e) * 4 + c] = zbuf[it];
        atomicAdd(&spart[c], accz);
        atomicAdd(&spart[4 + c], accz2);
    }
    __syncthreads();
    if (t < 8) atomicAdd(&accums[t], spart[t]);
}

// ---------------------------------------------------------------- K2
__global__ __launch_bounds__(256) void bn_apply(float* __restrict__ out,
                                                const float* __restrict__ accums,
                                                const float* __restrict__ gamma,
                                                const float* __restrict__ beta) {
    __shared__ float sc[8];
    const int t = threadIdx.x;
    if (t < 4) {
        float mu  = accums[t] * (1.0f / BATCH);
        float var = accums[4 + t] * (1.0f / BATCH) - mu * mu;
        float a = gamma[t] * rsqrtf(var + 1e-5f);
        sc[t]     = a;
        sc[4 + t] = beta[t] - mu * a;
    }
    __syncthreads();
    int i = blockIdx.x * 256 + t;   // one float4 (one image) each
    float4 z = ((float4*)out)[i];
    z.x = fmaf(z.x, sc[0], sc[4]);
    z.y = fmaf(z.y, sc[1], sc[5]);
    z.z = fmaf(z.z, sc[2], sc[6]);
    z.w = fmaf(z.w, sc[3], sc[7]);
    ((float4*)out)[i] = z;
}

extern "C" void kernel_launch(void* const* d_in, const int* in_sizes, int n_in,
                              void* d_out, int out_size, void* d_ws, size_t ws_size,
                              hipStream_t stream) {
    const float* x      = (const float*)d_in[0];
    const float* params = (const float*)d_in[1];
    const float* gamma  = (const float*)d_in[2];
    const float* beta   = (const float*)d_in[3];
    float* out = (float*)d_out;
    float* ws  = (float*)d_ws;

    hipMemsetAsync(ws, 0, 8 * sizeof(float), stream);   // zero BN accumulators
    hipLaunchKernelGGL(circuit_kernel, dim3(NBLK), dim3(256), 0, stream,
                       x, params, out, ws);
    hipLaunchKernelGGL(bn_apply, dim3(BATCH / 256), dim3(256), 0, stream,
                       out, ws, gamma, beta);
}